// Round 14
// baseline (149.046 us; speedup 1.0000x reference)
//
#include <hip/hip_runtime.h>
#include <hip/hip_bf16.h>

// Problem constants
#define D       512       // embedding dim (= C)
#define K       2048      // codebook size
#define HW      1024      // 32*32
#define N_TOK   16384     // 16*HW
#define NUMEL   8388608   // 16*512*32*32

typedef __attribute__((ext_vector_type(8))) short  short8;   // 8 bf16 = 4 VGPRs
typedef __attribute__((ext_vector_type(4))) float  floatx4;

// async global->LDS DMA, 16 B per lane; LDS dest is wave-uniform base + lane*16
#define GLD_LDS16(gptr, lptr) \
    __builtin_amdgcn_global_load_lds((const __attribute__((address_space(1))) void*)(gptr), \
                                     (__attribute__((address_space(3))) void*)(lptr), 16, 0, 0)

// ---- ws layout (bytes) ----
#define WS_EB    16777216    // bf16 [2048][512]
#define WS_ESQ   18874368    // f32  [2048]
#define WS_MINB  18882560    // u32  [16384] packed (21-bit dist key | 11-bit idx); memset 0xFF
#define WS_PZ    18948096    // f32  [64]   per-mtile sum z^2 partials (written by kg ntile==0)
#define WS_PARTS 18956288    // f32  [256]  per-image decoded-key partials (16 used)
#define WS_CNT2  18957312    // u32  [1]    completion counter (memset 0)

// monotone fp32 -> sortable u32, and its inverse
__device__ __forceinline__ unsigned int fkey(float f) {
    unsigned int b = __float_as_uint(f);
    return b ^ ((unsigned int)((int)b >> 31) | 0x80000000u);
}
__device__ __forceinline__ float unfkey(unsigned int u) {
    unsigned int b = (u & 0x80000000u) ? (u ^ 0x80000000u) : ~u;
    return __uint_as_float(b);
}

// ---------------- Kernel PE: emb -> eb bf16 + esq (tiny; R6-verified emb path) ----------------
__global__ __launch_bounds__(256) void kpe(const float* __restrict__ emb,
                                           __hip_bfloat16* __restrict__ eb,
                                           float* __restrict__ esq) {
    int blk = blockIdx.x;            // 0..255, 8 rows each
    int tid = threadIdx.x;
    int h = tid >> 5, l = tid & 31;
    int row = blk * 8 + h;
    const float* ep = emb + (size_t)row * D;
    __hip_bfloat16* op = eb + (size_t)row * D;
    float s = 0.f;
#pragma unroll
    for (int j = 0; j < 4; ++j) {
        float4 v = *(const float4*)(ep + l * 4 + j * 128);
        s += v.x * v.x + v.y * v.y + v.z * v.z + v.w * v.w;
        __hip_bfloat16 q0 = __float2bfloat16(v.x);
        __hip_bfloat16 q1 = __float2bfloat16(v.y);
        __hip_bfloat16 q2 = __float2bfloat16(v.z);
        __hip_bfloat16 q3 = __float2bfloat16(v.w);
        ushort4 u;
        u.x = *(unsigned short*)&q0; u.y = *(unsigned short*)&q1;
        u.z = *(unsigned short*)&q2; u.w = *(unsigned short*)&q3;
        *(ushort4*)(op + l * 4 + j * 128) = u;
    }
#pragma unroll
    for (int o = 16; o; o >>= 1) s += __shfl_down(s, o, 32);
    if (l == 0) esq[row] = s;
}

// ---------------- Kernel G7: G2 ring-of-4 + A staged DIRECTLY from z (fp32->bf16 in-kernel) ----------------
// Eliminates the zb intermediate (50 MB HBM round-trip + the z-transpose kernel). Per subtile,
// each thread: 16 coalesced dword loads from z (one K-subtile's 32ch x its token, loaded one
// iteration AHEAD), cvt to bf16, 2 swizzled ds_write_b128 into the SAME LDS layout G2's GLD
// produced (LDS[tok][g] = global granule g^key(tok&15)). B unchanged (GLD from eb). z^2 partial
// accumulated for free in ntile==0 blocks' staging regs -> pz[mtile]. K-rotation (anti-camping).
// Waits re-derived: steady vmcnt(20) (=GB(s+2)2 + LA(s+3)16 + GB(s+3)2), tail 2/0; the
// compiler's implicit wait at WRITEA (vmcnt(2)) enforces the A-data dependency.
__global__ __launch_bounds__(512, 2) void kg(const float* __restrict__ z,
                                             const __hip_bfloat16* __restrict__ eb,
                                             const float* __restrict__ esq,
                                             unsigned int* __restrict__ minb,
                                             float* __restrict__ pz) {
    __shared__ __hip_bfloat16 As[4][256 * 32];   // 4 ring slots, 16 KiB each
    __shared__ __hip_bfloat16 Bs[4][256 * 32];
    __shared__ float pzred[8];

    int bid   = blockIdx.x;
    int swzb  = (bid & 7) * 64 + (bid >> 3);     // XCD swizzle (L2-fit per XCD)
    int mtile = swzb >> 3;            // 0..63
    int ntile = swzb & 7;             // 0..7

    int tid  = threadIdx.x;
    int wv   = tid >> 6;              // 0..7
    int lane = tid & 63;
    int wm   = wv >> 2, wnn = wv & 3; // 2x4 wave grid, wave tile 128(M) x 64(N)
    int lrow = lane & 15, lquad = lane >> 4;
    int rl4  = lane >> 2, c4 = lane & 3;       // B staging lane map
    int csw  = c4 ^ ((lane >> 3) & 3);         // B store-side swizzled global uint4 col
    int kR   = (lrow >> 1) & 3;                // read-side swizzle key

    // A source: z NCHW, image b_img, tokens hw0..hw0+255, fp32
    int b_img = mtile >> 2;
    int hw0   = (mtile & 3) * 256;
    int tA    = tid & 255;                     // my token (lane-consecutive -> coalesced)
    int gbase = (tid >> 8) * 2;                // my 2 granules (8ch each): {0,1} or {2,3}
    int keyA  = ((tA & 15) >> 1) & 3;
    int wrA0  = tA * 32 + (((gbase    ) ^ keyA) << 3);   // LDS elem offsets (swizzled)
    int wrA1  = tA * 32 + (((gbase + 1) ^ keyA) << 3);
    const float* zT = z + (size_t)b_img * 512 * HW + hw0 + tA;
    bool nt0 = (ntile == 0);

    const uint4* Bg = (const uint4*)(eb + (size_t)ntile * 256 * D);

    floatx4 acc[8][4];
#pragma unroll
    for (int f = 0; f < 8; ++f)
#pragma unroll
        for (int g = 0; g < 4; ++g) acc[f][g] = (floatx4){0.f, 0.f, 0.f, 0.f};

    float rb[16];
    float zs = 0.f;

    // K-rotation: co-XCD sharers of one z-window start at different K-subtiles
#define TTK(t_) (((t_) + ntile) & 15)

    // load A-subtile kt into regs: 16 coalesced dword loads (ch-stride 4 KB)
#define LOADA(kt) do {                                                                     \
        const float* zp_ = zT + (size_t)((kt) * 32 + gbase * 8) * HW;                      \
        _Pragma("unroll")                                                                  \
        for (int j = 0; j < 16; ++j) rb[j] = zp_[(size_t)j * HW];                          \
    } while (0)

    // write regs (pipeline slot x) into As[x&3] with the G2 swizzle; accumulate z^2 on nt0
#define WRITEA(x) do {                                                                     \
        __hip_bfloat16* dst_ = &As[(x) & 3][0];                                            \
        short8 w0, w1;                                                                     \
        _Pragma("unroll")                                                                  \
        for (int j = 0; j < 8; ++j) {                                                      \
            __hip_bfloat16 q = __float2bfloat16(rb[j]);     w0[j] = *(short*)&q;           \
        }                                                                                  \
        _Pragma("unroll")                                                                  \
        for (int j = 0; j < 8; ++j) {                                                      \
            __hip_bfloat16 q = __float2bfloat16(rb[8 + j]); w1[j] = *(short*)&q;           \
        }                                                                                  \
        *(short8*)&dst_[wrA0] = w0;                                                        \
        *(short8*)&dst_[wrA1] = w1;                                                        \
        if (nt0) {                                                                         \
            _Pragma("unroll")                                                              \
            for (int j = 0; j < 16; ++j) zs += rb[j] * rb[j];                              \
        }                                                                                  \
    } while (0)

    // B staging unchanged: 2 GLD per wave into slot x&3, data subtile kt
#define GLDB(x, kt) do {                                                                   \
        const int slot_ = (x) & 3;                                                         \
        GLD_LDS16(Bg + (size_t)(      wv * 16 + rl4) * 64 + (kt) * 4 + csw,                \
                  &Bs[slot_][(      wv * 16) * 32]);                                       \
        GLD_LDS16(Bg + (size_t)(128 + wv * 16 + rl4) * 64 + (kt) * 4 + csw,                \
                  &Bs[slot_][(128 + wv * 16) * 32]);                                       \
    } while (0)

#define STEP(sl) do {                                                                      \
        short8 bfr[4], af[4];                                                              \
        _Pragma("unroll")                                                                  \
        for (int g = 0; g < 4; ++g)                                                        \
            bfr[g] = *(const short8*)&Bs[sl][(wnn * 64 + g * 16 + lrow) * 32 + ((lquad ^ kR) << 3)]; \
        _Pragma("unroll")                                                                  \
        for (int f = 0; f < 4; ++f)                                                        \
            af[f] = *(const short8*)&As[sl][(wm * 128 + f * 16 + lrow) * 32 + ((lquad ^ kR) << 3)]; \
        __builtin_amdgcn_s_setprio(1);                                                     \
        _Pragma("unroll")                                                                  \
        for (int f = 0; f < 4; ++f)                                                        \
            _Pragma("unroll")                                                              \
            for (int g = 0; g < 4; ++g)                                                    \
                acc[f][g] = __builtin_amdgcn_mfma_f32_16x16x32_bf16(af[f], bfr[g], acc[f][g], 0, 0, 0); \
        __builtin_amdgcn_s_setprio(0);                                                     \
        _Pragma("unroll")                                                                  \
        for (int f = 0; f < 4; ++f)                                                        \
            af[f] = *(const short8*)&As[sl][(wm * 128 + 64 + f * 16 + lrow) * 32 + ((lquad ^ kR) << 3)]; \
        __builtin_amdgcn_s_setprio(1);                                                     \
        _Pragma("unroll")                                                                  \
        for (int f = 0; f < 4; ++f)                                                        \
            _Pragma("unroll")                                                              \
            for (int g = 0; g < 4; ++g)                                                    \
                acc[f + 4][g] = __builtin_amdgcn_mfma_f32_16x16x32_bf16(af[f], bfr[g], acc[f + 4][g], 0, 0, 0); \
        __builtin_amdgcn_s_setprio(0);                                                     \
    } while (0)

    // ---- prologue: subtiles 0,1 written; 2 loaded; B 0..2 in flight ----
    LOADA(TTK(0)); GLDB(0, TTK(0));
    WRITEA(0);                        // implicit vmcnt wait for rb(0)
    LOADA(TTK(1)); GLDB(1, TTK(1));
    WRITEA(1);
    LOADA(TTK(2)); GLDB(2, TTK(2));
    asm volatile("s_waitcnt vmcnt(18) lgkmcnt(0)" ::: "memory");   // GB(0),GB(1) landed; LA(2)16+GB(2)2 in flight
    __builtin_amdgcn_s_barrier();
    __builtin_amdgcn_sched_barrier(0);

    // ---- main loop: iter s = {WRITEA(s+2); LOADA/GLDB(s+3); STEP(s); counted waits; barrier} ----
#pragma unroll 16
    for (int s = 0; s < 16; ++s) {
        if (s + 2 < 16) WRITEA(s + 2);                       // waits LA(s+2) (issued iter s-1)
        if (s + 3 < 16) { LOADA(TTK(s + 3)); GLDB(s + 3, TTK(s + 3)); }
        STEP(s & 3);
        __builtin_amdgcn_sched_barrier(0);
        if (s <= 12)      asm volatile("s_waitcnt vmcnt(20) lgkmcnt(0)" ::: "memory");
        else if (s == 13) asm volatile("s_waitcnt vmcnt(2) lgkmcnt(0)" ::: "memory");
        else if (s == 14) asm volatile("s_waitcnt vmcnt(0) lgkmcnt(0)" ::: "memory");
        if (s < 15) __builtin_amdgcn_s_barrier();
        __builtin_amdgcn_sched_barrier(0);
    }
#undef STEP
#undef GLDB
#undef WRITEA
#undef LOADA
#undef TTK

    // ---- z^2 partial: wave reduce -> pzred (read after the epilogue's barrier) ----
    if (nt0) {
#pragma unroll
        for (int o = 32; o; o >>= 1) zs += __shfl_down(zs, o);
        if (lane == 0) pzred[wv] = zs;
    }

    // ---- epilogue: dist = esq[n] - 2*dot; per-wave argmin, LDS combine, 1 atomicMin/row ----
    float es[4];
#pragma unroll
    for (int g = 0; g < 4; ++g) es[g] = esq[ntile * 256 + wnn * 64 + g * 16 + lrow];

    unsigned int* scr = (unsigned int*)&As[0][0];   // slot 0 dead (last subtile used slot 3)
#pragma unroll
    for (int f = 0; f < 8; ++f) {
#pragma unroll
        for (int r = 0; r < 4; ++r) {
            unsigned int best = 0xFFFFFFFFu;
#pragma unroll
            for (int g = 0; g < 4; ++g) {
                float dist = es[g] - 2.0f * acc[f][g][r];
                unsigned int kidx = (unsigned int)(ntile * 256 + wnn * 64 + g * 16 + lrow);
                unsigned int p = (fkey(dist) & 0xFFFFF800u) | kidx;
                best = p < best ? p : best;
            }
#pragma unroll
            for (int o = 1; o < 16; o <<= 1) {
                unsigned int other = (unsigned int)__shfl_xor((int)best, o);
                best = other < best ? other : best;
            }
            if (lrow == 0)
                scr[wnn * 256 + wm * 128 + f * 16 + lquad * 4 + r] = best;
        }
    }
    __syncthreads();
    if (tid < 256) {
        unsigned int b0 = scr[tid];
        unsigned int b1 = scr[256 + tid];
        unsigned int b2 = scr[512 + tid];
        unsigned int b3 = scr[768 + tid];
        b0 = b1 < b0 ? b1 : b0;
        b2 = b3 < b2 ? b3 : b2;
        b0 = b2 < b0 ? b2 : b0;
        atomicMin(&minb[mtile * 256 + tid], b0);
    }
    if (nt0 && tid == 0) {
        float t = 0.f;
#pragma unroll
        for (int i = 0; i < 8; ++i) t += pzred[i];
        pz[mtile] = t;
    }
}

// ---------------- Kernel O5: gather + NCHW write + loss, contiguous panels (pz fold: 64) ----------------
__global__ __launch_bounds__(256) void ko3(const float* __restrict__ emb,
                                           const unsigned int* __restrict__ minb,
                                           const float* __restrict__ pz,
                                           float* __restrict__ out,
                                           float* __restrict__ parts,
                                           unsigned int* __restrict__ cnt2) {
    __shared__ int   idx[1024];
    __shared__ float qt[8][1024];
    __shared__ float red[4];
    __shared__ int finflag;
    int blk = blockIdx.x;            // 0..1023
    int b   = blk >> 6;              // image 0..15
    int cg  = blk & 63;              // channel group 0..63 (8 channels each)
    int c0  = cg * 8;
    int tid = threadIdx.x;

    if (tid == 0) finflag = 0;

    float lv = 0.f;
#pragma unroll
    for (int i = 0; i < 4; ++i) {
        int t = tid + 256 * i;
        unsigned int key = minb[b * 1024 + t];
        idx[t] = (int)(key & 0x7FFu);
        if (cg == 0) lv += unfkey(key & 0xFFFFF800u);
    }
    __syncthreads();

    if (cg == 0) {
#pragma unroll
        for (int o = 32; o; o >>= 1) lv += __shfl_down(lv, o);
        if ((tid & 63) == 0) red[tid >> 6] = lv;
        __syncthreads();
        if (tid == 0) {
            parts[b] = red[0] + red[1] + red[2] + red[3];
            __threadfence();
            finflag = (atomicAdd(cnt2, 1u) == 15u);
        }
    }

    int half = tid & 1;
    int tb   = tid >> 1;
#pragma unroll
    for (int i = 0; i < 8; ++i) {
        int t = tb + 128 * i;
        float4 v = *(const float4*)(emb + (size_t)idx[t] * D + c0 + half * 4);
        qt[half * 4 + 0][t] = v.x; qt[half * 4 + 1][t] = v.y;
        qt[half * 4 + 2][t] = v.z; qt[half * 4 + 3][t] = v.w;
    }
    __syncthreads();

    float4* ob = (float4*)(out + ((size_t)b * D + c0) * HW);
    const float4* qb = (const float4*)&qt[0][0];
#pragma unroll
    for (int i = 0; i < 8; ++i)
        ob[tid + 256 * i] = qb[tid + 256 * i];

    __syncthreads();
    if (finflag) {
        float sv = (tid < 16) ? atomicAdd(&parts[tid], 0.0f) : 0.f;
        if (tid < 64) sv += pz[tid];             // fold 64 z^2 partials (from kg)
#pragma unroll
        for (int o = 32; o; o >>= 1) sv += __shfl_down(sv, o);
        if ((tid & 63) == 0) red[tid >> 6] = sv;
        __syncthreads();
        if (tid == 0)
            out[NUMEL] = 1.25f * (red[0] + red[1] + red[2] + red[3]) / 8388608.0f;
    }
}

extern "C" void kernel_launch(void* const* d_in, const int* in_sizes, int n_in,
                              void* d_out, int out_size, void* d_ws, size_t ws_size,
                              hipStream_t stream) {
    const float* z   = (const float*)d_in[0];   // [16,512,32,32]
    const float* emb = (const float*)d_in[1];   // [2048,512]
    char* ws = (char*)d_ws;
    __hip_bfloat16* eb   = (__hip_bfloat16*)(ws + WS_EB);
    float*          esq  = (float*)(ws + WS_ESQ);
    unsigned int*   minb = (unsigned int*)(ws + WS_MINB);
    float*          pz   = (float*)(ws + WS_PZ);
    float*          parts= (float*)(ws + WS_PARTS);
    unsigned int*   cnt2 = (unsigned int*)(ws + WS_CNT2);
    float* out = (float*)d_out;

    hipMemsetAsync((void*)minb, 0xFF, (size_t)N_TOK * 4, stream);
    hipMemsetAsync((void*)cnt2, 0, 4, stream);
    kpe<<< 256, 256, 0, stream>>>(emb, eb, esq);
    kg <<< 512, 512, 0, stream>>>(z, eb, esq, minb, pz);
    ko3<<<1024, 256, 0, stream>>>(emb, minb, pz, out, parts, cnt2);
}